// Round 2
// baseline (454.362 us; speedup 1.0000x reference)
//
#include <hip/hip_runtime.h>

#define NUM_CELLS 8192
#define COLS 1024
#define RPB 4  // rows per block: amortizes new_active reads; keeps 2048 blocks (8/CU)

typedef float f4 __attribute__((ext_vector_type(4)));
typedef f4 f4u __attribute__((aligned(4)));  // 4B-aligned float4 for odd-offset W' region

// Pass 1: new_active (d_out[0..8191]), anomaly (d_out[16384]), learn-gate flag (ws[0])
__global__ __launch_bounds__(1024) void prep_kernel(
    const float* __restrict__ act_cols, const float* __restrict__ pred,
    const float* __restrict__ prev, float* __restrict__ out,
    float* __restrict__ ws) {
  const int t = threadIdx.x;  // one thread per column, 1024 threads
  float p[8];
  float colsum = 0.f;
#pragma unroll
  for (int k = 0; k < 8; k++) { p[k] = pred[t * 8 + k]; colsum += p[k]; }
  const bool has_pred = colsum > 0.f;
  const bool active = act_cols[t] > 0.f;
#pragma unroll
  for (int k = 0; k < 8; k++)
    out[t * 8 + k] = active ? (has_pred ? p[k] : 1.f) : 0.f;

  float nA = active ? 1.f : 0.f;
  float nP = (active && has_pred) ? 1.f : 0.f;
  float ps = 0.f;
#pragma unroll
  for (int k = 0; k < 8; k++) ps += prev[t * 8 + k];

#pragma unroll
  for (int off = 32; off; off >>= 1) {
    nA += __shfl_down(nA, off);
    nP += __shfl_down(nP, off);
    ps += __shfl_down(ps, off);
  }
  __shared__ float sA[16], sP[16], sS[16];
  const int wid = t >> 6;
  if ((t & 63) == 0) { sA[wid] = nA; sP[wid] = nP; sS[wid] = ps; }
  __syncthreads();
  if (t == 0) {
    float a = 0.f, pp = 0.f, s = 0.f;
    for (int i = 0; i < 16; i++) { a += sA[i]; pp += sP[i]; s += sS[i]; }
    out[2 * NUM_CELLS] = 1.0f - pp / fmaxf(a, 1.0f);  // anomaly
    ws[0] = (s > 0.f) ? 1.f : 0.f;                    // learn gate
  }
}

// Pass 2: fused (connected @ new_active) row-reduction + permanence update.
// RPB rows per block; 256 threads x 8 float4 = 8192 elements per row.
// new_active cached in 32 VGPRs across the row loop; W streamed nontemporal.
__global__ __launch_bounds__(256) void fused_kernel(
    const float* __restrict__ W, const float* __restrict__ prev,
    float* __restrict__ out, const float* __restrict__ ws) {
  const int t = threadIdx.x;
  const int row0 = blockIdx.x * RPB;
  const float gate = ws[0];

  // cache this thread's new_active chunks (identical for every row)
  f4 a[8];
  const f4* __restrict__ A4 = (const f4*)out;  // new_active at d_out[0..8191]
#pragma unroll
  for (int k = 0; k < 8; k++) a[k] = A4[k * 256 + t];

  float rsum[RPB];

#pragma unroll 1
  for (int r = 0; r < RPB; r++) {
    const int row = row0 + r;
    const bool learn = (prev[row] * gate) > 0.f;  // block-uniform
    const f4* __restrict__ Wrow = (const f4*)(W + (size_t)row * NUM_CELLS);
    f4u* __restrict__ Wout = (f4u*)(out + 2 * NUM_CELLS + 1 + (size_t)row * NUM_CELLS);
    float sum = 0.f;
    if (learn) {
#pragma unroll
      for (int k = 0; k < 8; k++) {
        const int idx = k * 256 + t;
        const f4 w = __builtin_nontemporal_load(Wrow + idx);
        const f4 av = a[k];
        sum += ((w.x >= 0.5f) ? av.x : 0.f) + ((w.y >= 0.5f) ? av.y : 0.f) +
               ((w.z >= 0.5f) ? av.z : 0.f) + ((w.w >= 0.5f) ? av.w : 0.f);
        f4u u;
        u.x = fminf(fmaxf(w.x + ((av.x > 0.5f) ? 0.1f : -0.01f), 0.f), 1.f);
        u.y = fminf(fmaxf(w.y + ((av.y > 0.5f) ? 0.1f : -0.01f), 0.f), 1.f);
        u.z = fminf(fmaxf(w.z + ((av.z > 0.5f) ? 0.1f : -0.01f), 0.f), 1.f);
        u.w = fminf(fmaxf(w.w + ((av.w > 0.5f) ? 0.1f : -0.01f), 0.f), 1.f);
        __builtin_nontemporal_store(u, Wout + idx);
      }
    } else {
#pragma unroll
      for (int k = 0; k < 8; k++) {
        const int idx = k * 256 + t;
        const f4 w = __builtin_nontemporal_load(Wrow + idx);
        const f4 av = a[k];
        sum += ((w.x >= 0.5f) ? av.x : 0.f) + ((w.y >= 0.5f) ? av.y : 0.f) +
               ((w.z >= 0.5f) ? av.z : 0.f) + ((w.w >= 0.5f) ? av.w : 0.f);
        f4u u = {w.x, w.y, w.z, w.w};
        __builtin_nontemporal_store(u, Wout + idx);  // pass-through copy
      }
    }
    rsum[r] = sum;
  }

  // per-row block reductions (4 waves each)
  __shared__ float sred[RPB][4];
#pragma unroll
  for (int r = 0; r < RPB; r++) {
    float s = rsum[r];
#pragma unroll
    for (int off = 32; off; off >>= 1) s += __shfl_down(s, off);
    if ((t & 63) == 0) sred[r][t >> 6] = s;
  }
  __syncthreads();
  if (t < RPB) {
    const float tot = sred[t][0] + sred[t][1] + sred[t][2] + sred[t][3];
    out[NUM_CELLS + row0 + t] = (tot >= 13.0f) ? 1.f : 0.f;  // new_predictive
  }
}

extern "C" void kernel_launch(void* const* d_in, const int* in_sizes, int n_in,
                              void* d_out, int out_size, void* d_ws, size_t ws_size,
                              hipStream_t stream) {
  const float* act_cols = (const float*)d_in[0];  // [1024]
  const float* W = (const float*)d_in[1];         // [8192*8192]
  const float* pred = (const float*)d_in[2];      // [8192]
  const float* prev = (const float*)d_in[3];      // [8192]
  float* out = (float*)d_out;
  float* ws = (float*)d_ws;

  prep_kernel<<<1, 1024, 0, stream>>>(act_cols, pred, prev, out, ws);
  fused_kernel<<<NUM_CELLS / RPB, 256, 0, stream>>>(W, prev, out, ws);
}